// Round 4
// baseline (278.700 us; speedup 1.0000x reference)
//
#include <hip/hip_runtime.h>
#include <hip/hip_fp16.h>

// ProtoNet distance matrix: out[n,k] = (alpha+1e-16)^2 * (||x_n||^2 + ||p_k||^2 - 2 x_n.p_k)
// x: [16384,1024] f32, p: [2048,1024] f32, alpha: [1] f32, out: [16384,2048] f32.
//
// v2: cross-term GEMM upgraded from m97-structure (128^2, 2-barrier) to the
// 256^2 8-phase schedule (T2+T3+T4+T5): 8 waves (2Mx4N), BK=64, 128 KiB LDS
// double-buffer, per-phase {ds_read subtile | stage 1 half-tile | barrier |
// lgkmcnt(0) | setprio(1) MFMA x16 setprio(0) | barrier}, counted vmcnt(4)
// once per K-tile (never 0 in steady state).
//
// Stage stream: phase p stages half-tile s=p+6; per-tile ht order
// [B-lo, B-hi, A-lo, A-hi]. Quadrant walk (mlo,nlo)->(mlo,nhi)->(mhi,nhi)->
// (mhi,nlo). Invariants (desk-verified):
//  - same-buf stages (tile t+2) only in q2/q3, after region's last read+barrier
//  - entering tile t needs ht<=4t+3 landed: boundary vmcnt(4) (2 ht in flight)
//  - vmcnt(0) only at the boundary entering the last tile
// LDS swizzle: physical 16B slot = logical ^ (row&7), realized by pre-swizzled
// GLOBAL source (dest stays linear: uniform base + lane*16) — both-sides rule.

#define N_ROWS 16384
#define K_PROTO 2048
#define DIM 1024

#define BM 256
#define BN 256
#define BK 64
#define NT (DIM / BK)   // 16 K-tiles
#define NHT (4 * NT)    // 64 half-tiles

typedef _Float16 half8 __attribute__((ext_vector_type(8)));
typedef float f32x4 __attribute__((ext_vector_type(4)));

__device__ __forceinline__ void async_copy16(void* lds_dst, const void* g_src) {
    __builtin_amdgcn_global_load_lds(
        (const __attribute__((address_space(1))) void*)g_src,
        (__attribute__((address_space(3))) void*)lds_dst,
        16, 0, 0);
}

// ---------------- Pass 1: convert + row sum-of-squares (unchanged, verified) ----------------
__global__ __launch_bounds__(256) void convert_kernel(
    const float* __restrict__ x, const float* __restrict__ p,
    __half* __restrict__ xh, __half* __restrict__ ph,
    float* __restrict__ xsq, float* __restrict__ psq)
{
    int row = blockIdx.x;
    const float* src;
    __half* dst;
    float* sq;
    if (row < N_ROWS) {
        src = x + (size_t)row * DIM;
        dst = xh + (size_t)row * DIM;
        sq = xsq + row;
    } else {
        int r = row - N_ROWS;
        src = p + (size_t)r * DIM;
        dst = ph + (size_t)r * DIM;
        sq = psq + r;
    }
    int t = threadIdx.x;  // 256 threads x 4 floats = 1024
    float4 v = reinterpret_cast<const float4*>(src)[t];
    float s = v.x * v.x + v.y * v.y + v.z * v.z + v.w * v.w;

    union { __half2 h[2]; uint2 u; } pk;
    pk.h[0] = __floats2half2_rn(v.x, v.y);
    pk.h[1] = __floats2half2_rn(v.z, v.w);
    reinterpret_cast<uint2*>(dst)[t] = pk.u;

    #pragma unroll
    for (int off = 32; off > 0; off >>= 1) s += __shfl_down(s, off);
    __shared__ float red[4];
    if ((t & 63) == 0) red[t >> 6] = s;
    __syncthreads();
    if (t == 0) sq[0] = red[0] + red[1] + red[2] + red[3];
}

// ---------------- Pass 2: 256^2 8-phase fp16 MFMA GEMM ----------------
// grid = (16384/256)*(2048/256) = 64*8 = 512 blocks, 512 threads (8 waves 2Mx4N).
// LDS (dynamic, 128 KiB): buf b at b*65536: A[256][64]f16 @0, B[256][64]f16 @32768.

#define LDA(mo)                                                                      \
    do {                                                                             \
        _Pragma("unroll")                                                            \
        for (int m_ = 0; m_ < 4; ++m_) {                                             \
            const int row_ = wm * 128 + ((mo) + m_) * 16 + rr;                       \
            _Pragma("unroll")                                                        \
            for (int kk_ = 0; kk_ < 2; ++kk_)                                        \
                Af[m_][kk_] = *(const half8*)(Ab + row_ * 128 +                      \
                                   (((kk_ * 4 + lq) ^ (row_ & 7)) << 4));            \
        }                                                                            \
    } while (0)

#define LDB(n)                                                                       \
    do {                                                                             \
        const int row_ = wn * 64 + (n) * 16 + rr;                                    \
        _Pragma("unroll")                                                            \
        for (int kk_ = 0; kk_ < 2; ++kk_)                                            \
            Bf[n][kk_] = *(const half8*)(Bb + row_ * 128 +                           \
                               (((kk_ * 4 + lq) ^ (row_ & 7)) << 4));                \
    } while (0)

#define MMA8(mo, n0)                                                                 \
    do {                                                                             \
        _Pragma("unroll")                                                            \
        for (int m_ = 0; m_ < 4; ++m_)                                               \
            _Pragma("unroll")                                                        \
            for (int n_ = 0; n_ < 2; ++n_)                                           \
                _Pragma("unroll")                                                    \
                for (int kk_ = 0; kk_ < 2; ++kk_)                                    \
                    acc[(mo) + m_][(n0) + n_] =                                      \
                        __builtin_amdgcn_mfma_f32_16x16x32_f16(                      \
                            Af[m_][kk_], Bf[(n0) + n_][kk_],                         \
                            acc[(mo) + m_][(n0) + n_], 0, 0, 0);                     \
    } while (0)

#define PHASE_MID()                                                                  \
    __builtin_amdgcn_s_barrier();                                                    \
    asm volatile("s_waitcnt lgkmcnt(0)" ::: "memory");                               \
    __builtin_amdgcn_s_setprio(1)

#define PHASE_END()                                                                  \
    __builtin_amdgcn_s_setprio(0);                                                   \
    __builtin_amdgcn_s_barrier()

__global__ __launch_bounds__(512, 2) void gemm8_kernel(
    const __half* __restrict__ xh, const __half* __restrict__ ph,
    const float* __restrict__ xsq, const float* __restrict__ psq,
    const float* __restrict__ alpha, float* __restrict__ out)
{
    extern __shared__ char lds[];   // 131072 bytes

    const int tid = threadIdx.x;
    const int w = tid >> 6, lane = tid & 63;
    const int wm = w >> 2, wn = w & 3;       // 2 waves M x 4 waves N
    const int rr = lane & 15, lq = lane >> 4;

    // XCD-aware swizzle (nwg=512, 512%8==0 -> simple form bijective).
    // XCD x owns bm in [8x,8x+8) x all bn: A 4MB + B 4MB working set per XCD.
    const int bid = blockIdx.x;
    const int swz = (bid & 7) * 64 + (bid >> 3);
    const int bm = swz >> 3, bn = swz & 7;

    const __half* Abase = xh + (size_t)bm * BM * DIM;
    const __half* Bbase = ph + (size_t)bn * BN * DIM;

    f32x4 acc[8][4];
    #pragma unroll
    for (int m = 0; m < 8; ++m)
        #pragma unroll
        for (int n = 0; n < 4; ++n)
            acc[m][n] = (f32x4)0.0f;

    // half-tile s: tile T=s>>2, j=s&3: 0=B rows0-127, 1=B rows128-255,
    //                                  2=A rows0-127, 3=A rows128-255
    auto stage_ht = [&](int s) {
        if (s >= NHT) return;
        const int T = s >> 2, j = s & 3;
        char* buf = lds + (size_t)(T & 1) * 65536;
        const bool isA = (j >= 2);
        const int rowoff = (j & 1) << 7;                 // 0 or 128
        const __half* gb = isA ? Abase : Bbase;
        char* region = buf + (isA ? 0 : 32768) + rowoff * 128;
        #pragma unroll
        for (int i = 0; i < 2; ++i) {
            const int c = i * 512 + tid;                 // 0..1023
            const int r = c >> 3;                        // 0..127
            const int sl = (c & 7) ^ (r & 7);            // pre-swizzled source slot
            async_copy16(region + c * 16,
                         gb + (size_t)(rowoff + r) * DIM + T * BK + sl * 8);
        }
    };

    half8 Af[4][2], Bf[4][2];
    const char *Ab, *Bb;

    // prologue: stage ht 0..5 (tile0 all + tile1 B halves); need ht<=3 landed
    #pragma unroll
    for (int s = 0; s < 6; ++s) stage_ht(s);
    asm volatile("s_waitcnt vmcnt(4)" ::: "memory");
    __builtin_amdgcn_s_barrier();

    for (int t = 0; t < NT; ++t) {
        const char* base = lds + (size_t)(t & 1) * 65536;
        Ab = base; Bb = base + 32768;
        const int p = t * 4;

        // q0: (mlo, nlo) — stages A-lo(t+1) [other buf]
        LDA(0); LDB(0); LDB(1);
        stage_ht(p + 6);
        PHASE_MID();
        MMA8(0, 0);
        PHASE_END();

        // q1: (mlo, nhi) — stages A-hi(t+1) [other buf]
        LDB(2); LDB(3);
        stage_ht(p + 7);
        PHASE_MID();
        MMA8(0, 2);
        PHASE_END();

        // q2: (mhi, nhi) — stages B-lo(t+2) [cur buf; B fully read after q1]
        LDA(4);
        stage_ht(p + 8);
        PHASE_MID();
        MMA8(4, 2);
        PHASE_END();

        // q3: (mhi, nlo) — stages B-hi(t+2) [cur buf]; boundary vmcnt
        stage_ht(p + 9);
        __builtin_amdgcn_s_barrier();
        asm volatile("s_waitcnt lgkmcnt(0)" ::: "memory");
        __builtin_amdgcn_s_setprio(1);
        MMA8(4, 0);
        __builtin_amdgcn_s_setprio(0);
        if (t == NT - 2)
            asm volatile("s_waitcnt vmcnt(0)" ::: "memory");
        else if (t < NT - 2)
            asm volatile("s_waitcnt vmcnt(4)" ::: "memory");
        __builtin_amdgcn_s_barrier();
    }

    // epilogue: out = scale * (xsq[row] + psq[col] - 2*cross)
    const float a = alpha[0] + 1e-16f;
    const float scale = a * a;
    const int row0 = bm * BM + wm * 128 + lq * 4;
    const int col0 = bn * BN + wn * 64 + rr;
    #pragma unroll
    for (int n = 0; n < 4; ++n) {
        const int col = col0 + n * 16;
        const float pv = psq[col];
        #pragma unroll
        for (int m = 0; m < 8; ++m) {
            const int rbase = row0 + m * 16;
            #pragma unroll
            for (int r = 0; r < 4; ++r) {
                const int row = rbase + r;
                out[(size_t)row * K_PROTO + col] =
                    scale * (xsq[row] + pv - 2.0f * acc[m][n][r]);
            }
        }
    }
}

// ---------------- Fallback: direct fp32, no workspace (unchanged) ----------------
__global__ __launch_bounds__(256) void fallback_kernel(
    const float* __restrict__ x, const float* __restrict__ p,
    const float* __restrict__ alpha, float* __restrict__ out)
{
    __shared__ float xs[DIM];
    int n = blockIdx.x;
    int t = threadIdx.x;
    reinterpret_cast<float4*>(xs)[t] = reinterpret_cast<const float4*>(x + (size_t)n * DIM)[t];
    __syncthreads();
    const float a = alpha[0] + 1e-16f;
    const float scale = a * a;
    for (int j = 0; j < K_PROTO / 256; ++j) {
        int k = j * 256 + t;
        const float4* pr = reinterpret_cast<const float4*>(p + (size_t)k * DIM);
        float s = 0.0f;
        #pragma unroll 8
        for (int d4 = 0; d4 < DIM / 4; ++d4) {
            float4 pv = pr[d4];
            float dx = xs[d4 * 4 + 0] - pv.x;
            float dy = xs[d4 * 4 + 1] - pv.y;
            float dz = xs[d4 * 4 + 2] - pv.z;
            float dw = xs[d4 * 4 + 3] - pv.w;
            s += dx * dx + dy * dy + dz * dz + dw * dw;
        }
        out[(size_t)n * K_PROTO + k] = scale * s;
    }
}

extern "C" void kernel_launch(void* const* d_in, const int* in_sizes, int n_in,
                              void* d_out, int out_size, void* d_ws, size_t ws_size,
                              hipStream_t stream) {
    const float* x = (const float*)d_in[0];
    const float* p = (const float*)d_in[1];
    const float* alpha = (const float*)d_in[2];
    float* out = (float*)d_out;

    const size_t XH_BYTES = (size_t)N_ROWS * DIM * sizeof(__half);   // 32 MB
    const size_t PH_BYTES = (size_t)K_PROTO * DIM * sizeof(__half);  // 4 MB
    const size_t NEED = XH_BYTES + PH_BYTES +
                        (size_t)(N_ROWS + K_PROTO) * sizeof(float);

    if (ws_size < NEED) {
        fallback_kernel<<<dim3(N_ROWS), dim3(256), 0, stream>>>(x, p, alpha, out);
        return;
    }

    char* w = (char*)d_ws;
    __half* xh = (__half*)w;
    __half* ph = (__half*)(w + XH_BYTES);
    float* xsq = (float*)(w + XH_BYTES + PH_BYTES);
    float* psq = (float*)(w + XH_BYTES + PH_BYTES + N_ROWS * sizeof(float));

    convert_kernel<<<dim3(N_ROWS + K_PROTO), dim3(256), 0, stream>>>(
        x, p, xh, ph, xsq, psq);
    gemm8_kernel<<<dim3((N_ROWS / BM) * (K_PROTO / BN)), dim3(512), 131072, stream>>>(
        xh, ph, xsq, psq, alpha, out);
}